// Round 1
// baseline (67.419 us; speedup 1.0000x reference)
//
#include <hip/hip_runtime.h>

#define NTHREADS 256
#define N_FEAT   8192
#define EPT      (N_FEAT / NTHREADS)   // 32 elements per thread

// float -> order-preserving unsigned key
__device__ __forceinline__ unsigned f2k(float f) {
    unsigned u = __float_as_uint(f);
    return u ^ (unsigned)(((int)u >> 31) | 0x80000000);
}
// exact inverse
__device__ __forceinline__ float k2f(unsigned kk) {
    return __uint_as_float(kk ^ (unsigned)(((int)(~kk) >> 31) | 0x80000000));
}

__global__ __launch_bounds__(NTHREADS) void ksparse_kernel(
    const float* __restrict__ x, const int* __restrict__ kptr,
    float* __restrict__ out) {
    const int row = blockIdx.x;
    const int t   = threadIdx.x;
    const size_t base = (size_t)row * N_FEAT;

    __shared__ unsigned hist[256];
    __shared__ unsigned s_prefix;
    __shared__ unsigned s_r;

    // ---- load 32 elems (8 x float4) and convert to sortable keys ----
    const float4* xv = (const float4*)(x + base);
    unsigned key[EPT];
#pragma unroll
    for (int i = 0; i < 8; ++i) {
        float4 v = xv[t + i * NTHREADS];
        key[4 * i + 0] = f2k(v.x);
        key[4 * i + 1] = f2k(v.y);
        key[4 * i + 2] = f2k(v.z);
        key[4 * i + 3] = f2k(v.w);
    }

    int r = kptr[0] + 1;          // rank from the top: (k+1)-th largest
    unsigned prefix = 0;          // decided high bits of the kth key
    unsigned pmask  = 0;          // mask of decided bits

#pragma unroll
    for (int pass = 0; pass < 4; ++pass) {
        const int shift = 24 - pass * 8;

        hist[t] = 0;
        __syncthreads();

#pragma unroll
        for (int i = 0; i < EPT; ++i) {
            unsigned kk = key[i];
            if ((kk & pmask) == prefix)
                atomicAdd(&hist[(kk >> shift) & 0xFFu], 1u);
        }
        __syncthreads();

        // wave 0 (t<64): suffix-scan the 256 buckets, find bucket holding rank r
        if (t < 64) {
            unsigned h0 = hist[4 * t + 0];
            unsigned h1 = hist[4 * t + 1];
            unsigned h2 = hist[4 * t + 2];
            unsigned h3 = hist[4 * t + 3];
            // local suffix sums (from high bucket down)
            unsigned ls3 = h3;
            unsigned ls2 = h2 + ls3;
            unsigned ls1 = h1 + ls2;
            unsigned ls0 = h0 + ls1;
            unsigned C = ls0;
            // inclusive suffix scan of per-lane totals across the wave
            int S = (int)C;
#pragma unroll
            for (int off = 1; off < 64; off <<= 1) {
                int v = __shfl_down(S, off, 64);
                if (t + off < 64) S += v;
            }
            unsigned carry = (unsigned)S - C;   // sum of all lanes above
            unsigned ge, gt;
            unsigned ur = (unsigned)r;
#pragma unroll
            for (int j = 0; j < 4; ++j) {
                unsigned lsj  = (j == 0) ? ls0 : (j == 1) ? ls1 : (j == 2) ? ls2 : ls3;
                unsigned lsj1 = (j == 0) ? ls1 : (j == 1) ? ls2 : (j == 2) ? ls3 : 0u;
                ge = lsj + carry;
                gt = lsj1 + carry;
                if (ge >= ur && gt < ur) {
                    s_prefix = prefix | ((unsigned)(4 * t + j) << shift);
                    s_r      = ur - gt;
                }
            }
        }
        __syncthreads();
        prefix = s_prefix;
        r      = (int)s_r;
        pmask |= (0xFFu << shift);
    }

    // ---- write masked output ----
    const unsigned kth = prefix;   // exact key of the (k+1)-th largest
    float4* ov = (float4*)(out + base);
#pragma unroll
    for (int i = 0; i < 8; ++i) {
        float4 o;
        unsigned k0 = key[4 * i + 0];
        unsigned k1 = key[4 * i + 1];
        unsigned k2 = key[4 * i + 2];
        unsigned k3 = key[4 * i + 3];
        o.x = (k0 > kth) ? k2f(k0) : 0.0f;
        o.y = (k1 > kth) ? k2f(k1) : 0.0f;
        o.z = (k2 > kth) ? k2f(k2) : 0.0f;
        o.w = (k3 > kth) ? k2f(k3) : 0.0f;
        ov[t + i * NTHREADS] = o;
    }
}

extern "C" void kernel_launch(void* const* d_in, const int* in_sizes, int n_in,
                              void* d_out, int out_size, void* d_ws, size_t ws_size,
                              hipStream_t stream) {
    const float* x = (const float*)d_in[0];
    const int* k   = (const int*)d_in[1];
    float* out     = (float*)d_out;
    const int B = in_sizes[0] / N_FEAT;
    ksparse_kernel<<<B, NTHREADS, 0, stream>>>(x, k, out);
}

// Round 2
// 63.346 us; speedup vs baseline: 1.0643x; 1.0643x over previous
//
#include <hip/hip_runtime.h>

#define NTHREADS 512
#define N_FEAT   8192
#define EPT      (N_FEAT / NTHREADS)   // 16 elements per thread

// float -> order-preserving unsigned key
__device__ __forceinline__ unsigned f2k(float f) {
    unsigned u = __float_as_uint(f);
    return u ^ (unsigned)(((int)u >> 31) | 0x80000000);
}
// exact inverse
__device__ __forceinline__ float k2f(unsigned kk) {
    return __uint_as_float(kk ^ (unsigned)(((int)(~kk) >> 31) | 0x80000000));
}

// One radix-select pass over NB buckets at bit offset SHIFT.
// Histogram is stored skewed: phys(idx) = idx + (idx >> log2(NB/64)), so both
// the atomics and the wave-0 rank scan (lane stride PER+1, odd) are
// bank-conflict-free.
template<int NB, int SHIFT, bool FILTER>
__device__ __forceinline__ void radix_pass(unsigned* hist, const unsigned (&key)[EPT],
                                           unsigned& prefix, unsigned& pmask, unsigned& r,
                                           unsigned* s_pr, int t) {
    constexpr int PER = NB / 64;              // buckets per scan lane
    constexpr int L2P = (PER == 64) ? 6 : 4;  // log2(PER)
    constexpr int PHYS = NB + 64;             // skewed size

    // clear
#pragma unroll
    for (int i = 0; i < (PHYS + NTHREADS - 1) / NTHREADS; ++i) {
        int idx = t + i * NTHREADS;
        if (idx < PHYS) hist[idx] = 0;
    }
    __syncthreads();

    // histogram (skewed addressing)
#pragma unroll
    for (int i = 0; i < EPT; ++i) {
        unsigned kk = key[i];
        if (!FILTER || (kk & pmask) == prefix) {
            unsigned b = (kk >> SHIFT) & (NB - 1);
            atomicAdd(&hist[b + (b >> L2P)], 1u);
        }
    }
    __syncthreads();

    // wave 0: find the bucket containing rank r (counted from the top)
    if (t < 64) {
        const unsigned* hbase = hist + t * (PER + 1);   // skewed lane base
        unsigned C = 0;
#pragma unroll
        for (int j = 0; j < PER; ++j) C += hbase[j];
        unsigned S = C;                                  // inclusive suffix scan
#pragma unroll
        for (int off = 1; off < 64; off <<= 1) {
            unsigned v = (unsigned)__shfl_down((int)S, off, 64);
            if (t + off < 64) S += v;
        }
        unsigned carry = S - C;                          // sum of lanes above t
        if (S >= r && carry < r) {                       // exactly one lane
            unsigned acc = carry;                        // count strictly above bucket
#pragma unroll
            for (int j = PER - 1; j >= 0; --j) {
                unsigned ge = acc + hbase[j];
                if (ge >= r && acc < r) {
                    s_pr[0] = prefix | ((unsigned)(t * PER + j) << SHIFT);
                    s_pr[1] = r - acc;                   // rank within bucket
                }
                acc = ge;
            }
        }
    }
    __syncthreads();
    prefix = s_pr[0];
    r = s_pr[1];
    pmask |= (unsigned)(NB - 1) << SHIFT;
}

__global__ __launch_bounds__(NTHREADS) void ksparse_kernel(
    const float* __restrict__ x, const int* __restrict__ kptr,
    float* __restrict__ out) {
    const int row = blockIdx.x;
    const int t   = threadIdx.x;
    const size_t base = (size_t)row * N_FEAT;

    __shared__ unsigned hist[4096 + 64];
    __shared__ unsigned s_pr[2];

    // load 16 elems (4 x float4) -> sortable keys, kept in registers
    const float4* xv = (const float4*)(x + base);
    unsigned key[EPT];
#pragma unroll
    for (int i = 0; i < EPT / 4; ++i) {
        float4 v = xv[t + i * NTHREADS];
        key[4 * i + 0] = f2k(v.x);
        key[4 * i + 1] = f2k(v.y);
        key[4 * i + 2] = f2k(v.z);
        key[4 * i + 3] = f2k(v.w);
    }

    unsigned r = (unsigned)kptr[0] + 1u;   // (k+1)-th largest
    unsigned prefix = 0, pmask = 0;

    // 12 + 10 + 10 bits
    radix_pass<4096, 20, false>(hist, key, prefix, pmask, r, s_pr, t);
    radix_pass<1024, 10, true >(hist, key, prefix, pmask, r, s_pr, t);
    radix_pass<1024,  0, true >(hist, key, prefix, pmask, r, s_pr, t);

    const unsigned kth = prefix;           // exact key of the (k+1)-th largest
    float4* ov = (float4*)(out + base);
#pragma unroll
    for (int i = 0; i < EPT / 4; ++i) {
        float4 o;
        unsigned k0 = key[4 * i + 0];
        unsigned k1 = key[4 * i + 1];
        unsigned k2 = key[4 * i + 2];
        unsigned k3 = key[4 * i + 3];
        o.x = (k0 > kth) ? k2f(k0) : 0.0f;
        o.y = (k1 > kth) ? k2f(k1) : 0.0f;
        o.z = (k2 > kth) ? k2f(k2) : 0.0f;
        o.w = (k3 > kth) ? k2f(k3) : 0.0f;
        ov[t + i * NTHREADS] = o;
    }
}

extern "C" void kernel_launch(void* const* d_in, const int* in_sizes, int n_in,
                              void* d_out, int out_size, void* d_ws, size_t ws_size,
                              hipStream_t stream) {
    const float* x = (const float*)d_in[0];
    const int* k   = (const int*)d_in[1];
    float* out     = (float*)d_out;
    const int B = in_sizes[0] / N_FEAT;
    ksparse_kernel<<<B, NTHREADS, 0, stream>>>(x, k, out);
}

// Round 3
// 52.316 us; speedup vs baseline: 1.2887x; 1.2108x over previous
//
#include <hip/hip_runtime.h>

#define NTHREADS 512
#define N_FEAT   8192
#define EPT      (N_FEAT / NTHREADS)   // 16 elements per thread
#define NB0      4096                  // 12-bit first digit
#define CAP      2048                  // candidate buffer capacity

typedef float f4v __attribute__((ext_vector_type(4)));

// float -> order-preserving unsigned key (exact bijection)
__device__ __forceinline__ unsigned f2k(float f) {
    unsigned u = __float_as_uint(f);
    return u ^ (unsigned)(((int)u >> 31) | 0x80000000);
}
__device__ __forceinline__ float k2f(unsigned kk) {
    return __uint_as_float(kk ^ (unsigned)(((int)(~kk) >> 31) | 0x80000000));
}

__global__ __launch_bounds__(NTHREADS) void ksparse_kernel(
    const float* __restrict__ x, const int* __restrict__ kptr,
    float* __restrict__ out) {

    const int t    = threadIdx.x;
    const int lane = t & 63;
    const int w    = t >> 6;
    const size_t base = (size_t)blockIdx.x * N_FEAT;

    __shared__ unsigned hist[NB0];     // transposed: phys(b)=((b&7)<<9)|(b>>3)
    __shared__ unsigned cand[CAP];
    __shared__ unsigned ws[8];
    __shared__ unsigned s_bucket, s_r, s_cnt, s_kth;

    // ---- issue row loads (latency overlaps the histogram clear) ----
    const f4v* xv = (const f4v*)(x + base);
    f4v v0 = xv[t], v1 = xv[t + 512], v2 = xv[t + 1024], v3 = xv[t + 1536];

#pragma unroll
    for (int i = 0; i < NB0 / NTHREADS; ++i) hist[t + i * NTHREADS] = 0u;
    if (t == 0) s_cnt = 0u;
    __syncthreads();                                    // B1

    unsigned key[EPT];
#pragma unroll
    for (int j = 0; j < 4; ++j) {
        key[0 + j] = f2k(v0[j]);
        key[4 + j] = f2k(v1[j]);
        key[8 + j] = f2k(v2[j]);
        key[12 + j] = f2k(v3[j]);
    }

    const unsigned r = (unsigned)kptr[0] + 1u;          // (k+1)-th largest

    // ---- 12-bit histogram ----
#pragma unroll
    for (int i = 0; i < EPT; ++i) {
        unsigned b = key[i] >> 20;
        atomicAdd(&hist[((b & 7u) << 9) | (b >> 3)], 1u);
    }
    __syncthreads();                                    // B2

    // ---- all-thread suffix scan: thread t owns logical buckets [8t,8t+8) ----
    unsigned h[8], sum8 = 0;
#pragma unroll
    for (int j = 0; j < 8; ++j) { h[j] = hist[(j << 9) | t]; sum8 += h[j]; }
    unsigned S = sum8;                                  // wave inclusive suffix
#pragma unroll
    for (int off = 1; off < 64; off <<= 1) {
        unsigned q = (unsigned)__shfl_down((int)S, off, 64);
        if (lane + off < 64) S += q;
    }
    if (lane == 0) ws[w] = S;
    __syncthreads();                                    // B3
    unsigned above = S - sum8;                          // strictly above my chunk
#pragma unroll
    for (int w2 = 0; w2 < 8; ++w2) if (w2 > w) above += ws[w2];
    if (above < r && above + sum8 >= r) {               // exactly one thread
        unsigned acc = above;
#pragma unroll
        for (int j = 7; j >= 0; --j) {
            if (acc < r && acc + h[j] >= r) { s_bucket = (unsigned)(8 * t + j); s_r = r - acc; }
            acc += h[j];
        }
    }
    __syncthreads();                                    // B4
    const unsigned bucket = s_bucket;
    const unsigned r2 = s_r;                            // rank within bucket

    // ---- gather the bucket's candidates (typ. ~130 of 8192) ----
#pragma unroll
    for (int i = 0; i < EPT; ++i) {
        if ((key[i] >> 20) == bucket) {
            unsigned p = atomicAdd(&s_cnt, 1u);
            if (p < CAP) cand[p] = key[i];
        }
    }
    __syncthreads();                                    // B5
    const unsigned m = s_cnt;

    if (m <= CAP) {
        // exact rank by pairwise count (broadcast LDS reads, all waves)
        for (unsigned i = t; i < m; i += NTHREADS) {
            unsigned ki = cand[i], g = 0, ge = 0;
            for (unsigned j = 0; j < m; ++j) {
                unsigned kj = cand[j];
                g  += (kj > ki);
                ge += (kj >= ki);
            }
            if (g < r2 && ge >= r2) s_kth = ki;         // all writers write same value
        }
    } else {
        // never-taken on this data: finish with two radix-1024 passes
        unsigned prefix = bucket << 20;
        unsigned rr = r2;
        for (int pass = 0; pass < 2; ++pass) {
            const int shift = (pass == 0) ? 10 : 0;
            const unsigned hm = (pass == 0) ? 0xFFF00000u : 0xFFFFFC00u;
            hist[t] = 0u; hist[t + 512] = 0u;
            __syncthreads();
            for (int i = 0; i < EPT; ++i)
                if ((key[i] & hm) == prefix)
                    atomicAdd(&hist[(key[i] >> shift) & 1023u], 1u);
            __syncthreads();
            if (t < 64) {
                const unsigned* hb = hist + t * 16;
                unsigned C = 0;
                for (int j2 = 0; j2 < 16; ++j2) C += hb[j2];
                unsigned S2 = C;
                for (int off = 1; off < 64; off <<= 1) {
                    unsigned q = (unsigned)__shfl_down((int)S2, off, 64);
                    if (lane + off < 64) S2 += q;
                }
                unsigned carry = S2 - C;
                if (S2 >= rr && carry < rr) {
                    unsigned acc = carry;
                    for (int j2 = 15; j2 >= 0; --j2) {
                        unsigned ge2 = acc + hb[j2];
                        if (acc < rr && ge2 >= rr) { s_bucket = (unsigned)(t * 16 + j2); s_r = rr - acc; }
                        acc = ge2;
                    }
                }
            }
            __syncthreads();
            prefix |= s_bucket << shift;
            rr = s_r;
        }
        if (t == 0) s_kth = prefix;
    }
    __syncthreads();                                    // B6
    const unsigned kth = s_kth;

    // ---- masked write (nontemporal: don't evict L3-resident input) ----
    f4v* ov = (f4v*)(out + base);
#pragma unroll
    for (int i = 0; i < 4; ++i) {
        f4v o;
#pragma unroll
        for (int j = 0; j < 4; ++j) {
            unsigned kk = key[4 * i + j];
            o[j] = (kk > kth) ? k2f(kk) : 0.0f;
        }
        __builtin_nontemporal_store(o, ov + t + i * NTHREADS);
    }
}

extern "C" void kernel_launch(void* const* d_in, const int* in_sizes, int n_in,
                              void* d_out, int out_size, void* d_ws, size_t ws_size,
                              hipStream_t stream) {
    const float* x = (const float*)d_in[0];
    const int* k   = (const int*)d_in[1];
    float* out     = (float*)d_out;
    const int B = in_sizes[0] / N_FEAT;
    ksparse_kernel<<<B, NTHREADS, 0, stream>>>(x, k, out);
}